// Round 2
// baseline (695.489 us; speedup 1.0000x reference)
//
#include <hip/hip_runtime.h>

#define LL 200      // history length
#define DD 128      // attention dim
#define NH 4        // heads
#define HSTR 65     // hist LDS row stride in dwords (odd -> conflict-free both axes)
#define QTSTR 132   // q~ LDS row stride in floats
#define RSCALE 0.17677669529663687f   // 1/sqrt(32)

__device__ __forceinline__ float blo(unsigned int u) { return __uint_as_float(u << 16); }
__device__ __forceinline__ float bhi(unsigned int u) { return __uint_as_float(u & 0xffff0000u); }
__device__ __forceinline__ float b2f(unsigned short u) { return __uint_as_float(((unsigned int)u) << 16); }
__device__ __forceinline__ unsigned short f2bf(float f) {
  unsigned int u = __float_as_uint(f);
  u += 0x7fffu + ((u >> 16) & 1u);   // RNE
  return (unsigned short)(u >> 16);
}
__device__ __forceinline__ unsigned int pack2(float lo, float hi) {
  return ((unsigned int)f2bf(hi) << 16) | (unsigned int)f2bf(lo);
}

// dot of a 128-wide weight row (bf16 or f32) with a 128-float LDS vector
template <bool F32>
__device__ __forceinline__ float rowdot128(const void* __restrict__ wrow,
                                           const float* __restrict__ v) {
  float acc = 0.f;
  if constexpr (F32) {
    const float4* wr = (const float4*)wrow;
#pragma unroll
    for (int k = 0; k < 32; k++) {
      float4 w = wr[k];
      float4 vv = *(const float4*)(v + 4 * k);
      acc += w.x * vv.x + w.y * vv.y + w.z * vv.z + w.w * vv.w;
    }
  } else {
    const uint4* wr = (const uint4*)wrow;
#pragma unroll
    for (int k = 0; k < 16; k++) {
      uint4 u = wr[k];
      float4 v0 = *(const float4*)(v + k * 8);
      float4 v1 = *(const float4*)(v + k * 8 + 4);
      acc += blo(u.x) * v0.x + bhi(u.x) * v0.y + blo(u.y) * v0.z + bhi(u.y) * v0.w;
      acc += blo(u.z) * v1.x + bhi(u.z) * v1.y + blo(u.w) * v1.z + bhi(u.w) * v1.w;
    }
  }
  return acc;
}

template <bool F32>
__device__ __forceinline__ float welem(const void* w, size_t idx) {
  if constexpr (F32) return ((const float*)w)[idx];
  else               return b2f(((const unsigned short*)w)[idx]);
}

// dtype detector: for bf16 data, the LOW half of each dword is a bf16 normal
// (exp field ~[110,134] nearly always). For f32 data those bits are uniform
// mantissa bits (~10% in range). flag: 1 = f32, 0 = bf16.
__global__ void detect_dtype(const unsigned int* __restrict__ hist_dw, int* __restrict__ flag) {
  if (threadIdx.x == 0 && blockIdx.x == 0) {
    int cnt = 0;
    for (int i = 0; i < 256; i++) {
      unsigned int e = (hist_dw[i] >> 7) & 0xffu;
      cnt += (e >= 110u && e <= 134u) ? 1 : 0;
    }
    *flag = (cnt < 128) ? 1 : 0;
  }
}

template <bool F32>
__global__ __launch_bounds__(256, 2)
void mhta_kernel(const void* __restrict__ tgt,   // [B,128]
                 const void* __restrict__ hist,  // [B,200,128]
                 const int* __restrict__ mask,   // [B,200] i32
                 const void* __restrict__ Wq,    // [128,128]
                 const void* __restrict__ Wk,
                 const void* __restrict__ Wv,
                 const void* __restrict__ Wo,
                 void* __restrict__ out,         // [B,128]
                 const int* __restrict__ flag)
{
  __shared__ __align__(16) unsigned int sh_hist[LL * HSTR];  // bf16 pairs, padded rows
  __shared__ __align__(16) float sh_qt[NH * QTSTR];          // q~ per head; reused as cvec[512]
  __shared__ __align__(16) float sh_sc[LL * 4];              // scores -> attn, [l][h]
  __shared__ __align__(16) float sh_tvec[DD];                // target f32; reused as ovec
  __shared__ __align__(16) float sh_qv[DD];                  // q = Wq*t
  __shared__ __align__(16) float sh_cpart[2 * 512];          // c partials (2 chunks)

  if ((*flag != 0) != F32) return;   // dtype predicate (wave-uniform)

  const int tid = threadIdx.x;
  const int b = blockIdx.x;
  const float NINF = -__builtin_inff();

  // P0: target row -> f32 LDS
  if (tid < DD) sh_tvec[tid] = welem<F32>(tgt, (size_t)b * DD + tid);
  __syncthreads();

  // P1: q[i] = Wq[i,:] . t
  if (tid < DD) {
    const char* wrow = (const char*)Wq + (size_t)tid * DD * (F32 ? 4 : 2);
    sh_qv[tid] = rowdot128<F32>(wrow, sh_tvec);
  }
  __syncthreads();

  // P2: q~[h][j] = (1/sqrt(32)) * sum_d q[h*32+d] * Wk[h*32+d][j]
  for (int e = tid; e < NH * DD; e += 256) {
    int h = e >> 7, j = e & 127;
    float acc = 0.f;
#pragma unroll 8
    for (int d = 0; d < 32; d++)
      acc += sh_qv[h * 32 + d] * welem<F32>(Wk, (size_t)(h * 32 + d) * DD + j);
    sh_qt[h * QTSTR + j] = acc * RSCALE;
  }

  // P3: stage history row block into LDS as bf16 pairs (padded rows)
  if constexpr (F32) {
    const float2* hg = (const float2*)((const float*)hist + (size_t)b * LL * DD);
    for (int g = tid; g < LL * 64; g += 256) {        // g = l*64 + pair
      float2 f = hg[g];
      sh_hist[(g >> 6) * HSTR + (g & 63)] = pack2(f.x, f.y);
    }
  } else {
    const uint4* hg = (const uint4*)((const unsigned short*)hist + (size_t)b * LL * DD);
    for (int g = tid; g < LL * 16; g += 256) {        // 3200 x 16B
      uint4 u = hg[g];
      int l = g >> 4, q = (g & 15) << 2;
      unsigned int* dst = &sh_hist[l * HSTR + q];
      dst[0] = u.x; dst[1] = u.y; dst[2] = u.z; dst[3] = u.w;
    }
  }
  __syncthreads();

  // P4: scores[l][h] = q~[h] . hist[l]  (thread = row; q~ reads broadcast)
  if (tid < LL) {
    const int l = tid;
    float a0 = 0.f, a1 = 0.f, a2 = 0.f, a3 = 0.f;
    const unsigned int* hr = &sh_hist[l * HSTR];
#pragma unroll 4
    for (int j2 = 0; j2 < 64; j2++) {
      unsigned int dw = hr[j2];
      float f0 = blo(dw), f1 = bhi(dw);
      float2 q0 = *(const float2*)&sh_qt[0 * QTSTR + 2 * j2];
      float2 q1 = *(const float2*)&sh_qt[1 * QTSTR + 2 * j2];
      float2 q2 = *(const float2*)&sh_qt[2 * QTSTR + 2 * j2];
      float2 q3 = *(const float2*)&sh_qt[3 * QTSTR + 2 * j2];
      a0 += f0 * q0.x + f1 * q0.y;
      a1 += f0 * q1.x + f1 * q1.y;
      a2 += f0 * q2.x + f1 * q2.y;
      a3 += f0 * q3.x + f1 * q3.y;
    }
    bool mv = mask[(size_t)b * LL + l] != 0;
    float4 sv;
    sv.x = mv ? a0 : NINF;
    sv.y = mv ? a1 : NINF;
    sv.z = mv ? a2 : NINF;
    sv.w = mv ? a3 : NINF;
    *(float4*)&sh_sc[l * 4] = sv;
  }
  __syncthreads();

  // P5: per-head masked softmax over l (wave h = head h; shuffle reductions)
  {
    const int h = tid >> 6, lane = tid & 63;
    float v0 = sh_sc[lane * 4 + h];
    float v1 = sh_sc[(lane + 64) * 4 + h];
    float v2 = sh_sc[(lane + 128) * 4 + h];
    float v3 = (lane < 8) ? sh_sc[(lane + 192) * 4 + h] : NINF;
    float m = fmaxf(fmaxf(v0, v1), fmaxf(v2, v3));
#pragma unroll
    for (int off = 32; off; off >>= 1) m = fmaxf(m, __shfl_xor(m, off));
    float e0 = __expf(v0 - m), e1 = __expf(v1 - m), e2 = __expf(v2 - m);
    float e3 = (lane < 8) ? __expf(v3 - m) : 0.f;
    float s = e0 + e1 + e2 + e3;
#pragma unroll
    for (int off = 32; off; off >>= 1) s += __shfl_xor(s, off);
    float r = 1.f / s;
    sh_sc[lane * 4 + h] = e0 * r;
    sh_sc[(lane + 64) * 4 + h] = e1 * r;
    sh_sc[(lane + 128) * 4 + h] = e2 * r;
    if (lane < 8) sh_sc[(lane + 192) * 4 + h] = e3 * r;
  }
  __syncthreads();

  // P6: c[h][j] = sum_l attn[h][l] * hist[l][j]  (thread = column j, 2 row-chunks)
  {
    const int j = tid & 127, ch = tid >> 7;
    const int sh16 = (j & 1) << 4;
    float a0 = 0.f, a1 = 0.f, a2 = 0.f, a3 = 0.f;
    const int l0 = ch * 100;
#pragma unroll 4
    for (int l = l0; l < l0 + 100; l++) {
      unsigned int dw = sh_hist[l * HSTR + (j >> 1)];
      float f = __uint_as_float((dw >> sh16) << 16);
      float4 at = *(const float4*)&sh_sc[l * 4];   // wave-uniform broadcast
      a0 += f * at.x; a1 += f * at.y; a2 += f * at.z; a3 += f * at.w;
    }
    float* cp = &sh_cpart[ch * 512];
    cp[0 * DD + j] = a0; cp[1 * DD + j] = a1; cp[2 * DD + j] = a2; cp[3 * DD + j] = a3;
  }
  __syncthreads();

  // P7a: reduce chunk partials -> cvec (aliases sh_qt, dead after P4)
  float* cvec = sh_qt;
  for (int idx = tid; idx < 512; idx += 256)
    cvec[idx] = sh_cpart[idx] + sh_cpart[512 + idx];
  __syncthreads();

  // P7b: o[i] = Wv[i,:] . c[head(i)]  (ovec aliases sh_tvec, dead after P1)
  if (tid < DD) {
    const char* wrow = (const char*)Wv + (size_t)tid * DD * (F32 ? 4 : 2);
    sh_tvec[tid] = rowdot128<F32>(wrow, &cvec[(tid >> 5) * DD]);
  }
  __syncthreads();

  // P8: out[i'] = Wo[i',:] . o
  if (tid < DD) {
    const char* wrow = (const char*)Wo + (size_t)tid * DD * (F32 ? 4 : 2);
    float acc = rowdot128<F32>(wrow, sh_tvec);
    if constexpr (F32) ((float*)out)[(size_t)b * DD + tid] = acc;
    else               ((unsigned short*)out)[(size_t)b * DD + tid] = f2bf(acc);
  }
}

extern "C" void kernel_launch(void* const* d_in, const int* in_sizes, int n_in,
                              void* d_out, int out_size, void* d_ws, size_t ws_size,
                              hipStream_t stream) {
  const void* tgt  = d_in[0];
  const void* hist = d_in[1];
  const int*  mask = (const int*)d_in[2];
  const void* Wq   = d_in[3];
  const void* Wk   = d_in[4];
  const void* Wv   = d_in[5];
  const void* Wo   = d_in[6];

  const int B = in_sizes[0] / DD;   // 4096
  int* flag = (int*)d_ws;

  detect_dtype<<<dim3(1), dim3(64), 0, stream>>>((const unsigned int*)hist, flag);
  mhta_kernel<true ><<<dim3(B), dim3(256), 0, stream>>>(tgt, hist, mask, Wq, Wk, Wv, Wo, d_out, flag);
  mhta_kernel<false><<<dim3(B), dim3(256), 0, stream>>>(tgt, hist, mask, Wq, Wk, Wv, Wo, d_out, flag);
}